// Round 7
// baseline (197.856 us; speedup 1.0000x reference)
//
#include <hip/hip_runtime.h>
#include <hip/hip_bf16.h>
#include <math.h>

#define BB 4
#define NN 512
#define NP 516   // padded eb_lds row
#define DD 64
#define HH 8
#define DKK 8

typedef float f32x4 __attribute__((ext_vector_type(4)));
typedef short s16x8 __attribute__((ext_vector_type(8)));

// exact split fp32 -> bf16 hi (truncate) + bf16 lo (residual)
__device__ __forceinline__ void split8(const float* fv, s16x8& hi, s16x8& lo) {
#pragma unroll
    for (int j = 0; j < 8; ++j) {
        const unsigned u = __float_as_uint(fv[j]);
        hi[j] = (short)(u >> 16);
        const float r = fv[j] - __uint_as_float(u & 0xFFFF0000u);
        lo[j] = (short)(__float_as_uint(r) >> 16);
    }
}

__device__ __forceinline__ short bf16rne(float f) {
    return (short)((__float_as_uint(f) + 0x8000u) >> 16);
}

// ---------------- Kernel 1: QKV projection ----------------
__global__ __launch_bounds__(64) void qkv_kernel(
    const float* __restrict__ n,
    const float* __restrict__ Wq,
    const float* __restrict__ Wk,
    const float* __restrict__ Wv,
    float* __restrict__ Q,
    float* __restrict__ K,
    float* __restrict__ V)
{
    const int row = blockIdx.x;        // b*N + i
    const int j = threadIdx.x;         // 0..63
    __shared__ __align__(16) float nr[DD];
    nr[j] = n[(size_t)row * DD + j];
    __syncthreads();
    float q = 0.f, k = 0.f, v = 0.f;
#pragma unroll
    for (int d = 0; d < DD; ++d) {
        const float nv = nr[d];
        q = fmaf(nv, Wq[d * DD + j], q);
        k = fmaf(nv, Wk[d * DD + j], k);
        v = fmaf(nv, Wv[d * DD + j], v);
    }
    Q[(size_t)row * DD + j] = q;
    K[(size_t)row * DD + j] = k;
    V[(size_t)row * DD + j] = v;
}

// ---------------- Kernel 2: MFMA edge + attention ----------------
// Block = one (b,i), 4 waves. Wave w owns m in [128w,128w+128) as 8 tiles of 16.
// GEMM1 computed TRANSPOSED: C[c][m] = ([We|Wg]^T) @ e^T via mfma(Wfrag, efrag)
// -> Eb transpose for GEMM2 done with shfl_xor(16), no LDS round-trip.
__global__ __launch_bounds__(256, 4) void attn_kernel(
    const float* __restrict__ e,
    const float* __restrict__ Q,
    const float* __restrict__ K,
    const float* __restrict__ V,
    const float* __restrict__ We,   // [64][8]
    const float* __restrict__ Wg,   // [64][8]
    const float* __restrict__ Oe,   // [8][64]
    const float* __restrict__ On,   // [64][64]
    float* __restrict__ n_out,      // [B][N][64]
    float* __restrict__ e_out)      // [B][N][N][64]
{
    const int row = blockIdx.x;        // b*N + i
    const int b = row >> 9;
    const int t = threadIdx.x;
    const int lane = t & 63;
    const int wv = t >> 6;             // wave 0..3
    const int cc = lane & 15;
    const int kg = lane >> 4;          // 0..3

    __shared__ __align__(16) float q_lds[DD];
    __shared__ __align__(16) float eb_lds[HH][NP];
    __shared__ float gpart[4][HH];
    __shared__ float gsum[HH];
    __shared__ float vh_lds[DD];

    if (t < DD) q_lds[t] = Q[(size_t)row * DD + t];
    __syncthreads();

    // ---- Phase A: A_clip = clip(Q.K * scale) into eb_lds ----
    const float scale = 0.35355339059327373f;
    const float* __restrict__ Kb = K + (size_t)b * NN * DD;
    for (int mm = 0; mm < 2; ++mm) {
        const int m = t + mm * 256;
        const float4* __restrict__ kr = (const float4*)(Kb + (size_t)m * DD);
#pragma unroll
        for (int h = 0; h < HH; ++h) {
            const float4 k0 = kr[2 * h];
            const float4 k1 = kr[2 * h + 1];
            const float4 q0 = *(const float4*)&q_lds[h * 8];
            const float4 q1 = *(const float4*)&q_lds[h * 8 + 4];
            float a = q0.x * k0.x;
            a = fmaf(q0.y, k0.y, a);
            a = fmaf(q0.z, k0.z, a);
            a = fmaf(q0.w, k0.w, a);
            a = fmaf(q1.x, k1.x, a);
            a = fmaf(q1.y, k1.y, a);
            a = fmaf(q1.z, k1.z, a);
            a = fmaf(q1.w, k1.w, a);
            a *= scale;
            eb_lds[h][m] = fminf(fmaxf(a, -5.f), 5.f);
        }
    }
    __syncthreads();

    // ---- Weight fragments (register-resident) ----
    // W-frag (GEMM1 A operand): lane holds Wc[k=ks*32+kg*8+j][cc], Wc=[We|Wg]
    s16x8 b1h0, b1l0, b1h1, b1l1;
    {
        float fv[8];
#pragma unroll
        for (int j = 0; j < 8; ++j) {
            const int k = kg * 8 + j;
            fv[j] = (cc < 8) ? We[k * HH + cc] : Wg[k * HH + (cc - 8)];
        }
        split8(fv, b1h0, b1l0);
#pragma unroll
        for (int j = 0; j < 8; ++j) {
            const int k = 32 + kg * 8 + j;
            fv[j] = (cc < 8) ? We[k * HH + cc] : Wg[k * HH + (cc - 8)];
        }
        split8(fv, b1h1, b1l1);
    }
    // Oe frag (GEMM2 B operand): lane holds Oe[k=kg*8+j][nt*16+cc], kg==0 valid
    s16x8 b2h[4], b2l[4];
#pragma unroll
    for (int nt = 0; nt < 4; ++nt) {
        float fv[8];
#pragma unroll
        for (int j = 0; j < 8; ++j)
            fv[j] = (kg == 0) ? Oe[j * DD + nt * 16 + cc] : 0.f;
        split8(fv, b2h[nt], b2l[nt]);
    }

    float gs40 = 0.f, gs41 = 0.f, gs42 = 0.f, gs43 = 0.f;  // kg>=2: sigmoid sums
    const float* __restrict__ e_row = e + (size_t)row * NN * DD;
    float* __restrict__ eo = e_out + (size_t)row * NN * DD;
    const int T0 = wv * 8;
    const int lastT = T0 + 7;

    // two register prefetch buffers (A: even tiles, B: odd tiles)
    float4 A0, A1, A2, A3, B0, B1, B2, B3;
    {
        const float* s = e_row + (size_t)(T0 * 16 + cc) * DD + kg * 8;
        A0 = *(const float4*)s;        A1 = *(const float4*)(s + 4);
        A2 = *(const float4*)(s + 32); A3 = *(const float4*)(s + 36);
        const float* s2 = e_row + (size_t)((T0 + 1) * 16 + cc) * DD + kg * 8;
        B0 = *(const float4*)s2;        B1 = *(const float4*)(s2 + 4);
        B2 = *(const float4*)(s2 + 32); B3 = *(const float4*)(s2 + 36);
    }

    auto body = [&](int T, float4& p0, float4& p1, float4& p2, float4& p3) {
        const int m0 = T * 16;
        // convert buffer -> bf16 RNE frags (e operand of GEMM1 / B operand)
        s16x8 a1h0, a1h1;
        a1h0[0] = bf16rne(p0.x); a1h0[1] = bf16rne(p0.y);
        a1h0[2] = bf16rne(p0.z); a1h0[3] = bf16rne(p0.w);
        a1h0[4] = bf16rne(p1.x); a1h0[5] = bf16rne(p1.y);
        a1h0[6] = bf16rne(p1.z); a1h0[7] = bf16rne(p1.w);
        a1h1[0] = bf16rne(p2.x); a1h1[1] = bf16rne(p2.y);
        a1h1[2] = bf16rne(p2.z); a1h1[3] = bf16rne(p2.w);
        a1h1[4] = bf16rne(p3.x); a1h1[5] = bf16rne(p3.y);
        a1h1[6] = bf16rne(p3.z); a1h1[7] = bf16rne(p3.w);
        // reload this buffer with tile T+2 (in flight across ~2 bodies)
        {
            int Tn = T + 2; if (Tn > lastT) Tn = lastT;
            const float* s = e_row + (size_t)(Tn * 16 + cc) * DD + kg * 8;
            p0 = *(const float4*)s;        p1 = *(const float4*)(s + 4);
            p2 = *(const float4*)(s + 32); p3 = *(const float4*)(s + 36);
        }

        // GEMM1 transposed: C[c][m], c=kg*4+r, m=m0+cc   (4 MFMA)
        f32x4 acc = {0.f, 0.f, 0.f, 0.f};
        acc = __builtin_amdgcn_mfma_f32_16x16x32_bf16(b1h0, a1h0, acc, 0, 0, 0);
        acc = __builtin_amdgcn_mfma_f32_16x16x32_bf16(b1l0, a1h0, acc, 0, 0, 0);
        acc = __builtin_amdgcn_mfma_f32_16x16x32_bf16(b1h1, a1h1, acc, 0, 0, 0);
        acc = __builtin_amdgcn_mfma_f32_16x16x32_bf16(b1l1, a1h1, acc, 0, 0, 0);

        // post: kg<2 -> Eb rows (heads kg*4+r), kg>=2 -> sigmoid(G)
        float ebr0 = 0.f, ebr1 = 0.f, ebr2 = 0.f, ebr3 = 0.f;
        if (kg < 2) {
            const int h0 = kg * 4;
            const int m = m0 + cc;
            ebr0 = eb_lds[h0 + 0][m] + acc[0]; eb_lds[h0 + 0][m] = ebr0;
            ebr1 = eb_lds[h0 + 1][m] + acc[1]; eb_lds[h0 + 1][m] = ebr1;
            ebr2 = eb_lds[h0 + 2][m] + acc[2]; eb_lds[h0 + 2][m] = ebr2;
            ebr3 = eb_lds[h0 + 3][m] + acc[3]; eb_lds[h0 + 3][m] = ebr3;
        } else {
            gs40 += 1.f / (1.f + __expf(-acc[0]));
            gs41 += 1.f / (1.f + __expf(-acc[1]));
            gs42 += 1.f / (1.f + __expf(-acc[2]));
            gs43 += 1.f / (1.f + __expf(-acc[3]));
        }

        // merge heads 4..7 from partner lane (kg 0<->1) — replaces LDS round-trip
        const float pm0 = __shfl_xor(ebr0, 16, 64);
        const float pm1 = __shfl_xor(ebr1, 16, 64);
        const float pm2 = __shfl_xor(ebr2, 16, 64);
        const float pm3 = __shfl_xor(ebr3, 16, 64);

        s16x8 a2h, a2l;
        {
            float mj[8] = {ebr0, ebr1, ebr2, ebr3, pm0, pm1, pm2, pm3};
            split8(mj, a2h, a2l);
        }
        if (lane >= 16) {
            a2h = s16x8{0, 0, 0, 0, 0, 0, 0, 0};
            a2l = s16x8{0, 0, 0, 0, 0, 0, 0, 0};
        }

        // GEMM2: e_out[m][d] = Eb @ Oe  (12 MFMA)
#pragma unroll
        for (int nt = 0; nt < 4; ++nt) {
            f32x4 c2 = {0.f, 0.f, 0.f, 0.f};
            c2 = __builtin_amdgcn_mfma_f32_16x16x32_bf16(a2h, b2h[nt], c2, 0, 0, 0);
            c2 = __builtin_amdgcn_mfma_f32_16x16x32_bf16(a2l, b2h[nt], c2, 0, 0, 0);
            c2 = __builtin_amdgcn_mfma_f32_16x16x32_bf16(a2h, b2l[nt], c2, 0, 0, 0);
#pragma unroll
            for (int r = 0; r < 4; ++r) {
                const int m = m0 + kg * 4 + r;
                eo[(size_t)m * DD + nt * 16 + cc] = c2[r];
            }
        }
    };

#pragma unroll 1
    for (int s4 = 0; s4 < 4; ++s4) {
        body(T0 + 2 * s4,     A0, A1, A2, A3);
        body(T0 + 2 * s4 + 1, B0, B1, B2, B3);
    }

    // ---- G reduction: kg=2 lanes hold heads 0-3 partials, kg=3 heads 4-7 ----
    gs40 += __shfl_xor(gs40, 1, 64); gs40 += __shfl_xor(gs40, 2, 64);
    gs40 += __shfl_xor(gs40, 4, 64); gs40 += __shfl_xor(gs40, 8, 64);
    gs41 += __shfl_xor(gs41, 1, 64); gs41 += __shfl_xor(gs41, 2, 64);
    gs41 += __shfl_xor(gs41, 4, 64); gs41 += __shfl_xor(gs41, 8, 64);
    gs42 += __shfl_xor(gs42, 1, 64); gs42 += __shfl_xor(gs42, 2, 64);
    gs42 += __shfl_xor(gs42, 4, 64); gs42 += __shfl_xor(gs42, 8, 64);
    gs43 += __shfl_xor(gs43, 1, 64); gs43 += __shfl_xor(gs43, 2, 64);
    gs43 += __shfl_xor(gs43, 4, 64); gs43 += __shfl_xor(gs43, 8, 64);
    if (lane == 32) {
        gpart[wv][0] = gs40; gpart[wv][1] = gs41;
        gpart[wv][2] = gs42; gpart[wv][3] = gs43;
    }
    if (lane == 48) {
        gpart[wv][4] = gs40; gpart[wv][5] = gs41;
        gpart[wv][6] = gs42; gpart[wv][7] = gs43;
    }
    __syncthreads();
    if (t < HH) gsum[t] = gpart[0][t] + gpart[1][t] + gpart[2][t] + gpart[3][t];
    __syncthreads();

    // ---- softmax + PV: wave wv handles h = wv and wv+4 ----
    const float* __restrict__ Vb = V + (size_t)b * NN * DD;
#pragma unroll
    for (int hh = 0; hh < 2; ++hh) {
        const int h = wv + hh * 4;
        float x[8];
#pragma unroll
        for (int k = 0; k < 8; ++k) x[k] = eb_lds[h][lane + (k << 6)];
        float mx = x[0];
#pragma unroll
        for (int k = 1; k < 8; ++k) mx = fmaxf(mx, x[k]);
        mx = fmaxf(mx, __shfl_xor(mx, 1, 64));
        mx = fmaxf(mx, __shfl_xor(mx, 2, 64));
        mx = fmaxf(mx, __shfl_xor(mx, 4, 64));
        mx = fmaxf(mx, __shfl_xor(mx, 8, 64));
        mx = fmaxf(mx, __shfl_xor(mx, 16, 64));
        mx = fmaxf(mx, __shfl_xor(mx, 32, 64));
        float p[8];
        float s = 0.f;
#pragma unroll
        for (int k = 0; k < 8; ++k) { p[k] = __expf(x[k] - mx); s += p[k]; }
        s += __shfl_xor(s, 1, 64);
        s += __shfl_xor(s, 2, 64);
        s += __shfl_xor(s, 4, 64);
        s += __shfl_xor(s, 8, 64);
        s += __shfl_xor(s, 16, 64);
        s += __shfl_xor(s, 32, 64);

        float pv[8];
#pragma unroll
        for (int dk = 0; dk < 8; ++dk) pv[dk] = 0.f;
#pragma unroll
        for (int k = 0; k < 8; ++k) {
            const float* vr = Vb + (size_t)(lane + (k << 6)) * DD + h * DKK;
            const float4 va = *(const float4*)vr;
            const float4 vb2 = *(const float4*)(vr + 4);
            const float pk = p[k];
            pv[0] = fmaf(pk, va.x, pv[0]);
            pv[1] = fmaf(pk, va.y, pv[1]);
            pv[2] = fmaf(pk, va.z, pv[2]);
            pv[3] = fmaf(pk, va.w, pv[3]);
            pv[4] = fmaf(pk, vb2.x, pv[4]);
            pv[5] = fmaf(pk, vb2.y, pv[5]);
            pv[6] = fmaf(pk, vb2.z, pv[6]);
            pv[7] = fmaf(pk, vb2.w, pv[7]);
        }
#pragma unroll
        for (int dk = 0; dk < 8; ++dk) {
            float x2 = pv[dk];
            x2 += __shfl_xor(x2, 1, 64);
            x2 += __shfl_xor(x2, 2, 64);
            x2 += __shfl_xor(x2, 4, 64);
            x2 += __shfl_xor(x2, 8, 64);
            x2 += __shfl_xor(x2, 16, 64);
            x2 += __shfl_xor(x2, 32, 64);
            pv[dk] = x2;
        }
        if (lane == 0) {
            const float sc = log1pf(gsum[h]) / s;
#pragma unroll
            for (int dk = 0; dk < 8; ++dk) vh_lds[h * DKK + dk] = pv[dk] * sc;
        }
    }
    __syncthreads();

    // ---- n_out[b,i,:] = vh @ On ----
    if (t < DD) {
        const int j = t;
        float acc = 0.f;
#pragma unroll
        for (int d = 0; d < DD; ++d) acc = fmaf(vh_lds[d], On[d * DD + j], acc);
        n_out[(size_t)row * DD + j] = acc;
    }
}

extern "C" void kernel_launch(void* const* d_in, const int* in_sizes, int n_in,
                              void* d_out, int out_size, void* d_ws, size_t ws_size,
                              hipStream_t stream) {
    const float* n  = (const float*)d_in[0];
    const float* e  = (const float*)d_in[1];
    const float* Wq = (const float*)d_in[2];
    const float* Wk = (const float*)d_in[3];
    const float* Wv = (const float*)d_in[4];
    const float* On = (const float*)d_in[5];
    const float* We = (const float*)d_in[6];
    const float* Wg = (const float*)d_in[7];
    const float* Oe = (const float*)d_in[8];

    float* out = (float*)d_out;
    float* n_out = out;                                  // B*N*D floats
    float* e_out = out + (size_t)BB * NN * DD;           // B*N*N*D floats

    float* Q = (float*)d_ws;
    float* K = Q + (size_t)BB * NN * DD;
    float* V = K + (size_t)BB * NN * DD;

    qkv_kernel<<<BB * NN, 64, 0, stream>>>(n, Wq, Wk, Wv, Q, K, V);
    attn_kernel<<<BB * NN, 256, 0, stream>>>(e, Q, K, V, We, Wg, Oe, On, n_out, e_out);
}

// Round 8
// 185.807 us; speedup vs baseline: 1.0648x; 1.0648x over previous
//
#include <hip/hip_runtime.h>
#include <hip/hip_bf16.h>
#include <math.h>

#define BB 4
#define NN 512
#define NP 516   // padded eb_lds row
#define DD 64
#define HH 8
#define DKK 8

typedef float f32x4 __attribute__((ext_vector_type(4)));
typedef short s16x8 __attribute__((ext_vector_type(8)));

// exact split fp32 -> bf16 hi (truncate) + bf16 lo (residual)
__device__ __forceinline__ void split8(const float* fv, s16x8& hi, s16x8& lo) {
#pragma unroll
    for (int j = 0; j < 8; ++j) {
        const unsigned u = __float_as_uint(fv[j]);
        hi[j] = (short)(u >> 16);
        const float r = fv[j] - __uint_as_float(u & 0xFFFF0000u);
        lo[j] = (short)(__float_as_uint(r) >> 16);
    }
}

__device__ __forceinline__ short bf16rne(float f) {
    return (short)((__float_as_uint(f) + 0x8000u) >> 16);
}

// ---------------- Kernel 1: QKV projection ----------------
__global__ __launch_bounds__(64) void qkv_kernel(
    const float* __restrict__ n,
    const float* __restrict__ Wq,
    const float* __restrict__ Wk,
    const float* __restrict__ Wv,
    float* __restrict__ Q,
    float* __restrict__ K,
    float* __restrict__ V)
{
    const int row = blockIdx.x;        // b*N + i
    const int j = threadIdx.x;         // 0..63
    __shared__ __align__(16) float nr[DD];
    nr[j] = n[(size_t)row * DD + j];
    __syncthreads();
    float q = 0.f, k = 0.f, v = 0.f;
#pragma unroll
    for (int d = 0; d < DD; ++d) {
        const float nv = nr[d];
        q = fmaf(nv, Wq[d * DD + j], q);
        k = fmaf(nv, Wk[d * DD + j], k);
        v = fmaf(nv, Wv[d * DD + j], v);
    }
    Q[(size_t)row * DD + j] = q;
    K[(size_t)row * DD + j] = k;
    V[(size_t)row * DD + j] = v;
}

// ---------------- Kernel 2: MFMA edge + attention ----------------
// Block = one (b,i), 4 waves. Wave w owns m in [128w,128w+128).
// NO barrier until all streaming is done: phase A is per-wave (each wave
// computes A_clip for its own m-range only), then 8 stream bodies, then
// G-partials; first __syncthreads() only before softmax.
__global__ __launch_bounds__(256) void attn_kernel(
    const float* __restrict__ e,
    const float* __restrict__ Q,
    const float* __restrict__ K,
    const float* __restrict__ V,
    const float* __restrict__ We,   // [64][8]
    const float* __restrict__ Wg,   // [64][8]
    const float* __restrict__ Oe,   // [8][64]
    const float* __restrict__ On,   // [64][64]
    float* __restrict__ n_out,      // [B][N][64]
    float* __restrict__ e_out)      // [B][N][N][64]
{
    const int row = blockIdx.x;        // b*N + i
    const int b = row >> 9;
    const int t = threadIdx.x;
    const int lane = t & 63;
    const int wv = t >> 6;             // wave 0..3
    const int cc = lane & 15;
    const int kg = lane >> 4;          // 0..3

    __shared__ __align__(16) float eb_lds[HH][NP];
    __shared__ float gpart[4][HH];
    __shared__ float gsum[HH];
    __shared__ float vh_lds[DD];

    const float scale = 0.35355339059327373f;
    const float* __restrict__ Kb = K + (size_t)b * NN * DD;
    const float* __restrict__ Qr = Q + (size_t)row * DD;

    // ---- Phase A (per-wave, no barrier): A_clip for this wave's 128 rows ----
    for (int mm = 0; mm < 2; ++mm) {
        const int m = wv * 128 + lane + mm * 64;
        const float4* __restrict__ kr = (const float4*)(Kb + (size_t)m * DD);
        const float4* __restrict__ qr = (const float4*)Qr;
#pragma unroll
        for (int h = 0; h < HH; ++h) {
            const float4 k0 = kr[2 * h];
            const float4 k1 = kr[2 * h + 1];
            const float4 q0 = qr[2 * h];
            const float4 q1 = qr[2 * h + 1];
            float a = q0.x * k0.x;
            a = fmaf(q0.y, k0.y, a);
            a = fmaf(q0.z, k0.z, a);
            a = fmaf(q0.w, k0.w, a);
            a = fmaf(q1.x, k1.x, a);
            a = fmaf(q1.y, k1.y, a);
            a = fmaf(q1.z, k1.z, a);
            a = fmaf(q1.w, k1.w, a);
            a *= scale;
            eb_lds[h][m] = fminf(fmaxf(a, -5.f), 5.f);
        }
    }
    // no __syncthreads(): each wave reads back only its own eb_lds rows below

    // ---- Weight fragments (register-resident) ----
    s16x8 b1h0, b1l0, b1h1, b1l1;
    {
        float fv[8];
#pragma unroll
        for (int j = 0; j < 8; ++j) {
            const int k = kg * 8 + j;
            fv[j] = (cc < 8) ? We[k * HH + cc] : Wg[k * HH + (cc - 8)];
        }
        split8(fv, b1h0, b1l0);
#pragma unroll
        for (int j = 0; j < 8; ++j) {
            const int k = 32 + kg * 8 + j;
            fv[j] = (cc < 8) ? We[k * HH + cc] : Wg[k * HH + (cc - 8)];
        }
        split8(fv, b1h1, b1l1);
    }
    s16x8 b2h[4], b2l[4];
#pragma unroll
    for (int nt = 0; nt < 4; ++nt) {
        float fv[8];
#pragma unroll
        for (int j = 0; j < 8; ++j)
            fv[j] = (kg == 0) ? Oe[j * DD + nt * 16 + cc] : 0.f;
        split8(fv, b2h[nt], b2l[nt]);
    }

    float gs40 = 0.f, gs41 = 0.f, gs42 = 0.f, gs43 = 0.f;  // kg>=2: sigmoid sums
    const float* __restrict__ e_row = e + (size_t)row * NN * DD;
    float* __restrict__ eo = e_out + (size_t)row * NN * DD;
    const int T0 = wv * 8;
    const int lastT = T0 + 7;

    // two register prefetch buffers (A: even tiles, B: odd tiles)
    float4 A0, A1, A2, A3, B0, B1, B2, B3;
    {
        const float* s = e_row + (size_t)(T0 * 16 + cc) * DD + kg * 8;
        A0 = *(const float4*)s;        A1 = *(const float4*)(s + 4);
        A2 = *(const float4*)(s + 32); A3 = *(const float4*)(s + 36);
        const float* s2 = e_row + (size_t)((T0 + 1) * 16 + cc) * DD + kg * 8;
        B0 = *(const float4*)s2;        B1 = *(const float4*)(s2 + 4);
        B2 = *(const float4*)(s2 + 32); B3 = *(const float4*)(s2 + 36);
    }

    auto body = [&](int T, float4& p0, float4& p1, float4& p2, float4& p3) {
        const int m0 = T * 16;
        s16x8 a1h0, a1h1;
        a1h0[0] = bf16rne(p0.x); a1h0[1] = bf16rne(p0.y);
        a1h0[2] = bf16rne(p0.z); a1h0[3] = bf16rne(p0.w);
        a1h0[4] = bf16rne(p1.x); a1h0[5] = bf16rne(p1.y);
        a1h0[6] = bf16rne(p1.z); a1h0[7] = bf16rne(p1.w);
        a1h1[0] = bf16rne(p2.x); a1h1[1] = bf16rne(p2.y);
        a1h1[2] = bf16rne(p2.z); a1h1[3] = bf16rne(p2.w);
        a1h1[4] = bf16rne(p3.x); a1h1[5] = bf16rne(p3.y);
        a1h1[6] = bf16rne(p3.z); a1h1[7] = bf16rne(p3.w);
        // reload this buffer with tile T+2
        {
            int Tn = T + 2; if (Tn > lastT) Tn = lastT;
            const float* s = e_row + (size_t)(Tn * 16 + cc) * DD + kg * 8;
            p0 = *(const float4*)s;        p1 = *(const float4*)(s + 4);
            p2 = *(const float4*)(s + 32); p3 = *(const float4*)(s + 36);
        }

        // GEMM1 transposed: C[c][m], c=kg*4+r, m=m0+cc   (4 MFMA)
        f32x4 acc = {0.f, 0.f, 0.f, 0.f};
        acc = __builtin_amdgcn_mfma_f32_16x16x32_bf16(b1h0, a1h0, acc, 0, 0, 0);
        acc = __builtin_amdgcn_mfma_f32_16x16x32_bf16(b1l0, a1h0, acc, 0, 0, 0);
        acc = __builtin_amdgcn_mfma_f32_16x16x32_bf16(b1h1, a1h1, acc, 0, 0, 0);
        acc = __builtin_amdgcn_mfma_f32_16x16x32_bf16(b1l1, a1h1, acc, 0, 0, 0);

        float ebr0 = 0.f, ebr1 = 0.f, ebr2 = 0.f, ebr3 = 0.f;
        if (kg < 2) {
            const int h0 = kg * 4;
            const int m = m0 + cc;
            ebr0 = eb_lds[h0 + 0][m] + acc[0]; eb_lds[h0 + 0][m] = ebr0;
            ebr1 = eb_lds[h0 + 1][m] + acc[1]; eb_lds[h0 + 1][m] = ebr1;
            ebr2 = eb_lds[h0 + 2][m] + acc[2]; eb_lds[h0 + 2][m] = ebr2;
            ebr3 = eb_lds[h0 + 3][m] + acc[3]; eb_lds[h0 + 3][m] = ebr3;
        } else {
            gs40 += 1.f / (1.f + __expf(-acc[0]));
            gs41 += 1.f / (1.f + __expf(-acc[1]));
            gs42 += 1.f / (1.f + __expf(-acc[2]));
            gs43 += 1.f / (1.f + __expf(-acc[3]));
        }

        const float pm0 = __shfl_xor(ebr0, 16, 64);
        const float pm1 = __shfl_xor(ebr1, 16, 64);
        const float pm2 = __shfl_xor(ebr2, 16, 64);
        const float pm3 = __shfl_xor(ebr3, 16, 64);

        s16x8 a2h, a2l;
        {
            float mj[8] = {ebr0, ebr1, ebr2, ebr3, pm0, pm1, pm2, pm3};
            split8(mj, a2h, a2l);
        }
        if (lane >= 16) {
            a2h = s16x8{0, 0, 0, 0, 0, 0, 0, 0};
            a2l = s16x8{0, 0, 0, 0, 0, 0, 0, 0};
        }

        // GEMM2: e_out[m][d] = Eb @ Oe  (12 MFMA)
#pragma unroll
        for (int nt = 0; nt < 4; ++nt) {
            f32x4 c2 = {0.f, 0.f, 0.f, 0.f};
            c2 = __builtin_amdgcn_mfma_f32_16x16x32_bf16(a2h, b2h[nt], c2, 0, 0, 0);
            c2 = __builtin_amdgcn_mfma_f32_16x16x32_bf16(a2l, b2h[nt], c2, 0, 0, 0);
            c2 = __builtin_amdgcn_mfma_f32_16x16x32_bf16(a2h, b2l[nt], c2, 0, 0, 0);
#pragma unroll
            for (int r = 0; r < 4; ++r) {
                const int m = m0 + kg * 4 + r;
                eo[(size_t)m * DD + nt * 16 + cc] = c2[r];
            }
        }
    };

#pragma unroll 1
    for (int s4 = 0; s4 < 4; ++s4) {
        body(T0 + 2 * s4,     A0, A1, A2, A3);
        body(T0 + 2 * s4 + 1, B0, B1, B2, B3);
    }

    // ---- G reduction: kg=2 lanes hold heads 0-3 partials, kg=3 heads 4-7 ----
    gs40 += __shfl_xor(gs40, 1, 64); gs40 += __shfl_xor(gs40, 2, 64);
    gs40 += __shfl_xor(gs40, 4, 64); gs40 += __shfl_xor(gs40, 8, 64);
    gs41 += __shfl_xor(gs41, 1, 64); gs41 += __shfl_xor(gs41, 2, 64);
    gs41 += __shfl_xor(gs41, 4, 64); gs41 += __shfl_xor(gs41, 8, 64);
    gs42 += __shfl_xor(gs42, 1, 64); gs42 += __shfl_xor(gs42, 2, 64);
    gs42 += __shfl_xor(gs42, 4, 64); gs42 += __shfl_xor(gs42, 8, 64);
    gs43 += __shfl_xor(gs43, 1, 64); gs43 += __shfl_xor(gs43, 2, 64);
    gs43 += __shfl_xor(gs43, 4, 64); gs43 += __shfl_xor(gs43, 8, 64);
    if (lane == 32) {
        gpart[wv][0] = gs40; gpart[wv][1] = gs41;
        gpart[wv][2] = gs42; gpart[wv][3] = gs43;
    }
    if (lane == 48) {
        gpart[wv][4] = gs40; gpart[wv][5] = gs41;
        gpart[wv][6] = gs42; gpart[wv][7] = gs43;
    }
    __syncthreads();   // first block-wide sync: eb_lds complete + gpart ready
    if (t < HH) gsum[t] = gpart[0][t] + gpart[1][t] + gpart[2][t] + gpart[3][t];
    __syncthreads();

    // ---- softmax + PV: wave wv handles h = wv and wv+4 ----
    const float* __restrict__ Vb = V + (size_t)b * NN * DD;
#pragma unroll
    for (int hh = 0; hh < 2; ++hh) {
        const int h = wv + hh * 4;
        float x[8];
#pragma unroll
        for (int k = 0; k < 8; ++k) x[k] = eb_lds[h][lane + (k << 6)];
        float mx = x[0];
#pragma unroll
        for (int k = 1; k < 8; ++k) mx = fmaxf(mx, x[k]);
        mx = fmaxf(mx, __shfl_xor(mx, 1, 64));
        mx = fmaxf(mx, __shfl_xor(mx, 2, 64));
        mx = fmaxf(mx, __shfl_xor(mx, 4, 64));
        mx = fmaxf(mx, __shfl_xor(mx, 8, 64));
        mx = fmaxf(mx, __shfl_xor(mx, 16, 64));
        mx = fmaxf(mx, __shfl_xor(mx, 32, 64));
        float p[8];
        float s = 0.f;
#pragma unroll
        for (int k = 0; k < 8; ++k) { p[k] = __expf(x[k] - mx); s += p[k]; }
        s += __shfl_xor(s, 1, 64);
        s += __shfl_xor(s, 2, 64);
        s += __shfl_xor(s, 4, 64);
        s += __shfl_xor(s, 8, 64);
        s += __shfl_xor(s, 16, 64);
        s += __shfl_xor(s, 32, 64);

        float pv[8];
#pragma unroll
        for (int dk = 0; dk < 8; ++dk) pv[dk] = 0.f;
#pragma unroll
        for (int k = 0; k < 8; ++k) {
            const float* vr = Vb + (size_t)(lane + (k << 6)) * DD + h * DKK;
            const float4 va = *(const float4*)vr;
            const float4 vb2 = *(const float4*)(vr + 4);
            const float pk = p[k];
            pv[0] = fmaf(pk, va.x, pv[0]);
            pv[1] = fmaf(pk, va.y, pv[1]);
            pv[2] = fmaf(pk, va.z, pv[2]);
            pv[3] = fmaf(pk, va.w, pv[3]);
            pv[4] = fmaf(pk, vb2.x, pv[4]);
            pv[5] = fmaf(pk, vb2.y, pv[5]);
            pv[6] = fmaf(pk, vb2.z, pv[6]);
            pv[7] = fmaf(pk, vb2.w, pv[7]);
        }
#pragma unroll
        for (int dk = 0; dk < 8; ++dk) {
            float x2 = pv[dk];
            x2 += __shfl_xor(x2, 1, 64);
            x2 += __shfl_xor(x2, 2, 64);
            x2 += __shfl_xor(x2, 4, 64);
            x2 += __shfl_xor(x2, 8, 64);
            x2 += __shfl_xor(x2, 16, 64);
            x2 += __shfl_xor(x2, 32, 64);
            pv[dk] = x2;
        }
        if (lane == 0) {
            const float sc = log1pf(gsum[h]) / s;
#pragma unroll
            for (int dk = 0; dk < 8; ++dk) vh_lds[h * DKK + dk] = pv[dk] * sc;
        }
    }
    __syncthreads();

    // ---- n_out[b,i,:] = vh @ On ----
    if (t < DD) {
        const int j = t;
        float acc = 0.f;
#pragma unroll
        for (int d = 0; d < DD; ++d) acc = fmaf(vh_lds[d], On[d * DD + j], acc);
        n_out[(size_t)row * DD + j] = acc;
    }
}

extern "C" void kernel_launch(void* const* d_in, const int* in_sizes, int n_in,
                              void* d_out, int out_size, void* d_ws, size_t ws_size,
                              hipStream_t stream) {
    const float* n  = (const float*)d_in[0];
    const float* e  = (const float*)d_in[1];
    const float* Wq = (const float*)d_in[2];
    const float* Wk = (const float*)d_in[3];
    const float* Wv = (const float*)d_in[4];
    const float* On = (const float*)d_in[5];
    const float* We = (const float*)d_in[6];
    const float* Wg = (const float*)d_in[7];
    const float* Oe = (const float*)d_in[8];

    float* out = (float*)d_out;
    float* n_out = out;                                  // B*N*D floats
    float* e_out = out + (size_t)BB * NN * DD;           // B*N*N*D floats

    float* Q = (float*)d_ws;
    float* K = Q + (size_t)BB * NN * DD;
    float* V = K + (size_t)BB * NN * DD;

    qkv_kernel<<<BB * NN, 64, 0, stream>>>(n, Wq, Wk, Wv, Q, K, V);
    attn_kernel<<<BB * NN, 256, 0, stream>>>(e, Q, K, V, We, Wg, Oe, On, n_out, e_out);
}